// Round 6
// baseline (90.159 us; speedup 1.0000x reference)
//
#include <hip/hip_runtime.h>

#define Bn 2
#define Cn 3
#define Hn 160
#define Wn 160
#define SPANc 11
#define Kc 23
#define HWn (Hn * Wn)
#define PW 182                 // padded dim: 160 + 2*11
#define PP (PW * PW)
#define LAMc 0.15f
#define INVN (1.0f / (float)(Bn * HWn))
#define TJ 32                  // j-tile width (= lanes 0..31)
#define Gc 4                   // centers per thread (vertical)
#define TI 32                  // i-tile height = 8 ty-groups * Gc
#define NROW (TI + Kc - 1)     // 54 staged rows
#define NREC (NROW * TJ)       // 1728 records in LDS (16 B each = 27.6 KB)
#define CEXP (-0.72134752f)    // -0.5 * log2(e)
#define CX   (14.42695041f)    // 20 * 0.72134752  (cross-term scale)
#define CA   (0.72134752f)
#define NPREP ((Bn * PP + 255) / 256)   // 259 prep blocks
#define NCELL 64               // spread accumulator cells (256 B apart)
#define CELLSTRIDE 64          // floats between cells
#define NBLK (5 * 10 * 23)     // 1150 gcrf blocks

__device__ __forceinline__ float wave_reduce64(float v) {
#pragma unroll
    for (int off = 32; off > 0; off >>= 1) v += __shfl_down(v, off, 64);
    return v;
}

// pack two floats as bf16 (rne) into one uint: a in high 16, b in low 16
__device__ __forceinline__ unsigned int bf16pk(float a, float b) {
    unsigned int ua = __float_as_uint(a), ub = __float_as_uint(b);
    ua += 0x7fffu + ((ua >> 16) & 1u);
    ub += 0x7fffu + ((ub >> 16) & 1u);
    return (ua & 0xffff0000u) | (ub >> 16);
}

// Fused: zero halo + softmax/pack interior + CE block-partials (pre-scaled) +
// zero the 64 spread cells + zero the completion ticket.
// Record uint4: [pk(p0,p1), pk(p2,mB), pk(q0,q1), pk(q2,0)]
//   p = raw image, mB = -72.13*sum(p^2) (fp32-computed, bf16-stored), q = src*y.
// exp2 exponent identity: -0.7213*sum((c-10p)^2) = (14.427*sum(c*p)) - A - B.
__global__ __launch_bounds__(256) void prep_kernel(
    const float* __restrict__ logit, const int* __restrict__ target,
    const float* __restrict__ image, const float* __restrict__ srcmap,
    const float* __restrict__ dstmap, uint4* __restrict__ gU4,
    float4* __restrict__ cvec, float* __restrict__ pc, float* __restrict__ cells,
    unsigned int* __restrict__ ticket)
{
    int idx = blockIdx.x * 256 + threadIdx.x;
    float ce = 0.0f;
    if (idx < NCELL) cells[idx * CELLSTRIDE] = 0.0f;   // gcrf runs after (stream order)
    if (idx == 0) *ticket = 0u;
    if (idx < Bn * PP) {
        int b   = idx / PP;
        int rem = idx - b * PP;
        int ip  = rem / PW;
        int jp  = rem - ip * PW;
        int i = ip - SPANc, j = jp - SPANc;
        if ((unsigned)i < (unsigned)Hn && (unsigned)j < (unsigned)Wn) {
            int r = i * Wn + j;
            int p = b * HWn + r;
            const float* lg = logit + (size_t)b * Cn * HWn + r;
            float l0 = lg[0], l1 = lg[HWn], l2 = lg[2 * HWn];
            float m = fmaxf(l0, fmaxf(l1, l2));
            float e0 = __expf(l0 - m), e1 = __expf(l1 - m), e2 = __expf(l2 - m);
            float s = e0 + e1 + e2;
            float inv = 1.0f / s;
            float y0 = e0 * inv, y1 = e1 * inv, y2 = e2 * inv;
            float lse = m + __logf(s);

            const float* im = image + (size_t)b * 3 * HWn + r;
            float p0 = im[0], p1 = im[HWn], p2 = im[2 * HWn];
            float sv = srcmap[p];
            float dv = dstmap[p];

            float B = (p0 * p0 + p1 * p1 + p2 * p2) * (100.0f * CA);
            gU4[idx] = make_uint4(bf16pk(p0, p1), bf16pk(p2, -B),
                                  bf16pk(sv * y0, sv * y1), bf16pk(sv * y2, 0.0f));

            float md = LAMc * (1.0f - dv) * INVN;
            cvec[p] = make_float4(md * (1.0f - y0), md * (1.0f - y1),
                                  md * (1.0f - y2), 0.0f);

            int t = target[p];
            float lt = (t == 0) ? l0 : ((t == 1) ? l1 : l2);
            ce = (lse - lt) * dv * INVN;
        } else {
            gU4[idx] = make_uint4(0u, 0u, 0u, 0u);
        }
    }

    float v = wave_reduce64(ce);
    __shared__ float wsum[4];
    int tid = threadIdx.x;
    if ((tid & 63) == 0) wsum[tid >> 6] = v;
    __syncthreads();
    if (tid == 0) pc[blockIdx.x] = wsum[0] + wsum[1] + wsum[2] + wsum[3];
}

__device__ __forceinline__ void unpk(uint4 ru, float& p0, float& p1, float& p2,
                                     float& mB, float& q0, float& q1, float& q2) {
    p0 = __uint_as_float(ru.x & 0xffff0000u);
    p1 = __uint_as_float(ru.x << 16);
    p2 = __uint_as_float(ru.y & 0xffff0000u);
    mB = __uint_as_float(ru.y << 16);
    q0 = __uint_as_float(ru.z & 0xffff0000u);
    q1 = __uint_as_float(ru.z << 16);
    q2 = __uint_as_float(ru.w & 0xffff0000u);
}

// One tap. Non-XY: kA-factored — k = exp2(c.p + mB); the per-center exp2(mA)
// is applied once in the epilogue (7 VALU ops, shorter dep chain).
// XY: exact form k = exp2(e + mA) (+ xy kernel); epilogue scale is 1.
template<bool XY>
__device__ __forceinline__ void tap(float p0, float p1, float p2, float mB,
                                    float q0, float q1, float q2,
                                    float c0s, float c1s, float c2s, float mA,
                                    bool xy_on, float dy2, float dxv,
                                    float& e0, float& e1, float& e2)
{
    float e = fmaf(c0s, p0, fmaf(c1s, p1, fmaf(c2s, p2, mB)));
    float k;
    if constexpr (XY) {
        k = __builtin_amdgcn_exp2f(e + mA);
        if (xy_on) k += __builtin_amdgcn_exp2f(fmaf(dxv, dxv, dy2) * CEXP);
    } else {
        k = __builtin_amdgcn_exp2f(e);
    }
    e0 = fmaf(k, q0, e0);
    e1 = fmaf(k, q1, e1);
    e2 = fmaf(k, q2, e2);
}

template<bool XY>
__device__ __forceinline__ void row_taps(uint4 ru, int r,
    const float* c0s, const float* c1s, const float* c2s, const float* mA,
    bool xy_on, float dy2, float fi0, float eg[Gc][3], int clo, int chi)
{
    float p0, p1, p2, mB, q0, q1, q2;
    unpk(ru, p0, p1, p2, mB, q0, q1, q2);
    float dxb = XY ? (fi0 - (fi0 + (float)(r - SPANc)) * (1.0f / 6.0f)) : 0.0f;
#pragma unroll
    for (int c = 0; c < Gc; ++c) {
        if (c < clo || c > chi) continue;
        tap<XY>(p0, p1, p2, mB, q0, q1, q2, c0s[c], c1s[c], c2s[c], mA[c],
                xy_on, dy2, dxb + (float)c, eg[c][0], eg[c][1], eg[c][2]);
    }
}

// 3-phase window loop over staged LDS records (R0-proven shape).
template<bool XY>
__device__ __forceinline__ void window_loop(
    const uint4* sU4, int lbase,
    const float* c0s, const float* c1s, const float* c2s, const float* mA,
    bool xy_on, float dy2, float fi0, float eg[Gc][3])
{
#pragma unroll
    for (int r = 0; r < 3; ++r) {               // prologue (triangular): c <= r
        row_taps<XY>(sU4[lbase + r * TJ], r, c0s, c1s, c2s, mA,
                     xy_on, dy2, fi0, eg, 0, r);
    }
#pragma unroll 2
    for (int r = 3; r <= 22; ++r) {             // full rows: all 4 centers
        row_taps<XY>(sU4[lbase + r * TJ], r, c0s, c1s, c2s, mA,
                     xy_on, dy2, fi0, eg, 0, 3);
    }
#pragma unroll
    for (int r = 23; r <= 25; ++r) {            // epilogue (triangular): c >= r-22
        row_taps<XY>(sU4[lbase + r * TJ], r, c0s, c1s, c2s, mA,
                     xy_on, dy2, fi0, eg, r - 22, 3);
    }
}

// Window kernel. Grid: (5, 5*B, 23) = 1150 blocks. Block (32,8). One dj per block.
// Stage 54x32 uint4 records (27.6 KB LDS, 5 blocks/CU). Reduction sink: spread
// cells + completion ticket; the LAST block to finish (device-scope ticket)
// folds cells + CE partials and stores out[0] directly — no finalize dispatch.
__global__ __launch_bounds__(256, 5) void gcrf_kernel(
    const uint4* __restrict__ gU4, const float4* __restrict__ cvec,
    const float* __restrict__ pc, float* __restrict__ cells,
    unsigned int* __restrict__ ticket, float* __restrict__ out)
{
    __shared__ uint4 sU4[NREC];

    int tx = threadIdx.x;                 // 0..31 (j)
    int ty = threadIdx.y;                 // 0..7  (i-group)
    int tid = ty * TJ + tx;
    int jx = blockIdx.x;
    int j  = jx * TJ + tx;
    int by = blockIdx.y;
    int b  = by / 5;
    int it = by - b * 5;
    int i0g = it * TI + ty * Gc;          // first center row of this thread
    int dj = blockIdx.z;                  // 0..22

    size_t g0 = (size_t)b * PP + (size_t)(it * TI) * PW + (jx * TJ + dj);
    for (int n = tid; n < NREC; n += 256) {
        int rr = n >> 5, cc = n & 31;
        sU4[n] = gU4[g0 + (size_t)rr * PW + cc];
    }
    __syncthreads();

    bool isxy = (jx == 0 && it == 0);     // block-uniform

    int lbase = ty * Gc * TJ + tx;        // LDS index of (local row ty*Gc, col tx)
    float c0s[Gc], c1s[Gc], c2s[Gc], mA[Gc], kAe[Gc];
#pragma unroll
    for (int c = 0; c < Gc; ++c) {
        uint4 cu = sU4[lbase + (c + SPANc) * TJ];
        float cc0 = __uint_as_float(cu.x & 0xffff0000u);
        float cc1 = __uint_as_float(cu.x << 16);
        float cc2 = __uint_as_float(cu.y & 0xffff0000u);
        c0s[c] = cc0 * CX; c1s[c] = cc1 * CX; c2s[c] = cc2 * CX;
        mA[c] = -CA * fmaf(cc0, cc0, fmaf(cc1, cc1, cc2 * cc2));
        kAe[c] = isxy ? 1.0f : __builtin_amdgcn_exp2f(mA[c]);
    }

    // k_xy < 2.3e-29 unless both i<16 and j<16 (source-bug form: d = c - p/6)
    bool xy_on = (j < 16) && (i0g < 16);
    float dy = (float)j - (float)(j + dj - SPANc) * (1.0f / 6.0f);
    float dy2 = dy * dy;
    float fi0 = (float)i0g;

    float eg[Gc][3];
#pragma unroll
    for (int c = 0; c < Gc; ++c) { eg[c][0] = 0.f; eg[c][1] = 0.f; eg[c][2] = 0.f; }

    if (isxy) {   // only blocks where xy_on can hold
        window_loop<true>(sU4, lbase, c0s, c1s, c2s, mA, xy_on, dy2, fi0, eg);
    } else {
        window_loop<false>(sU4, lbase, c0s, c1s, c2s, mA, false, dy2, fi0, eg);
    }

    // epilogue: cvec already holds lam*(1-dst)*(1-y_c)/(B*HW); kAe folds back
    // the per-center exp2(mA) removed from the non-XY tap.
    const float4* cv = cvec + ((size_t)b * HWn + (size_t)i0g * Wn + j);
    float contrib = 0.0f;
#pragma unroll
    for (int c = 0; c < Gc; ++c) {
        float4 t = cv[(size_t)c * Wn];
        float d = eg[c][0] * t.x + eg[c][1] * t.y + eg[c][2] * t.z;
        contrib = fmaf(kAe[c], d, contrib);
    }

    float v = wave_reduce64(contrib);
    __shared__ float wsum[4];
    __shared__ int lastflag;
    if ((tid & 63) == 0) wsum[tid >> 6] = v;
    __syncthreads();
    if (tid == 0) {
        int bflat = (blockIdx.z * gridDim.y + blockIdx.y) * gridDim.x + blockIdx.x;
        atomicAdd(cells + (size_t)(bflat & (NCELL - 1)) * CELLSTRIDE,
                  wsum[0] + wsum[1] + wsum[2] + wsum[3]);
        __threadfence();                               // cell-add visible before ticket
        unsigned int old = atomicAdd(ticket, 1u);
        lastflag = (old == (unsigned int)(NBLK - 1));
    }
    __syncthreads();

    // Last-finisher folds the global sum. Cells are read via atomicAdd(+0.0f)
    // — served at the device-coherent point, immune to stale L1/XCD-L2 (G16).
    // pc[] was plain-stored by prep before this dispatch (kernel-boundary
    // visibility), so plain loads are safe for it.
    if (lastflag && tid < 64) {
        float s = atomicAdd(cells + (size_t)tid * CELLSTRIDE, 0.0f);
        for (int k = tid; k < NPREP; k += 64) s += pc[k];
        float v2 = wave_reduce64(s);
        if (tid == 0) out[0] = v2;
    }
}

extern "C" void kernel_launch(void* const* d_in, const int* in_sizes, int n_in,
                              void* d_out, int out_size, void* d_ws, size_t ws_size,
                              hipStream_t stream)
{
    const float* logit  = (const float*)d_in[0];
    const int*   target = (const int*)d_in[1];
    const float* image  = (const float*)d_in[2];
    const float* srcmap = (const float*)d_in[3];
    const float* dstmap = (const float*)d_in[4];
    float* out = (float*)d_out;

    const size_t NRECG = (size_t)Bn * PP;   // 66,248 padded records
    unsigned int* ticket = (unsigned int*)((char*)d_ws + 128);
    float*  pc    = (float*)((char*)d_ws + 256);                 // 259 CE partials
    float*  cells = (float*)((char*)d_ws + 4096);                // 64 cells, 256 B apart
    uint4*  gU4   = (uint4*)((char*)d_ws + 4096 + 16384);
    float4* cvec  = (float4*)((char*)d_ws + 4096 + 16384 + NRECG * 16);

    prep_kernel<<<NPREP, 256, 0, stream>>>(logit, target, image, srcmap, dstmap,
                                           gU4, cvec, pc, cells, ticket);
    dim3 grid(Wn / TJ, (Hn / TI) * Bn, Kc);
    dim3 blk(TJ, 8);
    gcrf_kernel<<<grid, blk, 0, stream>>>(gU4, cvec, pc, cells, ticket, out);
}

// Round 7
// 80.892 us; speedup vs baseline: 1.1146x; 1.1146x over previous
//
#include <hip/hip_runtime.h>

#define Bn 2
#define Cn 3
#define Hn 160
#define Wn 160
#define SPANc 11
#define Kc 23
#define HWn (Hn * Wn)
#define LAMc 0.15f
#define INVN (1.0f / (float)(Bn * HWn))
#define TJ 32                  // j-tile width (= lanes 0..31)
#define Gc 4                   // centers per thread (vertical)
#define TI 32                  // i-tile height = 8 ty-groups * Gc
#define NROW (TI + Kc - 1)     // 54 staged rows
#define NREC (NROW * TJ)       // 1728 records in LDS (16 B each = 27.6 KB)
#define CEXP (-0.72134752f)    // -0.5 * log2(e)
#define CX   (14.42695041f)    // 20 * 0.72134752  (cross-term scale)
#define CA   (0.72134752f)
#define NBLK (5 * 10 * 23)     // 1150 gcrf blocks

__device__ __forceinline__ float wave_reduce64(float v) {
#pragma unroll
    for (int off = 32; off > 0; off >>= 1) v += __shfl_down(v, off, 64);
    return v;
}

// pack two floats as bf16 (rne) into one uint: a in high 16, b in low 16
__device__ __forceinline__ unsigned int bf16pk(float a, float b) {
    unsigned int ua = __float_as_uint(a), ub = __float_as_uint(b);
    ua += 0x7fffu + ((ua >> 16) & 1u);
    ub += 0x7fffu + ((ub >> 16) & 1u);
    return (ua & 0xffff0000u) | (ub >> 16);
}

__device__ __forceinline__ void unpk(uint4 ru, float& p0, float& p1, float& p2,
                                     float& mB, float& q0, float& q1, float& q2) {
    p0 = __uint_as_float(ru.x & 0xffff0000u);
    p1 = __uint_as_float(ru.x << 16);
    p2 = __uint_as_float(ru.y & 0xffff0000u);
    mB = __uint_as_float(ru.y << 16);
    q0 = __uint_as_float(ru.z & 0xffff0000u);
    q1 = __uint_as_float(ru.z << 16);
    q2 = __uint_as_float(ru.w & 0xffff0000u);
}

// One tap. Non-XY: kA-factored — k = exp2(c.p + mB); the per-center exp2(mA)
// is applied once in the epilogue (7 VALU ops, shorter dep chain).
// XY: exact form k = exp2(e + mA) (+ xy kernel); epilogue scale is 1.
template<bool XY>
__device__ __forceinline__ void tap(float p0, float p1, float p2, float mB,
                                    float q0, float q1, float q2,
                                    float c0s, float c1s, float c2s, float mA,
                                    bool xy_on, float dy2, float dxv,
                                    float& e0, float& e1, float& e2)
{
    float e = fmaf(c0s, p0, fmaf(c1s, p1, fmaf(c2s, p2, mB)));
    float k;
    if constexpr (XY) {
        k = __builtin_amdgcn_exp2f(e + mA);
        if (xy_on) k += __builtin_amdgcn_exp2f(fmaf(dxv, dxv, dy2) * CEXP);
    } else {
        k = __builtin_amdgcn_exp2f(e);
    }
    e0 = fmaf(k, q0, e0);
    e1 = fmaf(k, q1, e1);
    e2 = fmaf(k, q2, e2);
}

template<bool XY>
__device__ __forceinline__ void row_taps(uint4 ru, int r,
    const float* c0s, const float* c1s, const float* c2s, const float* mA,
    bool xy_on, float dy2, float fi0, float eg[Gc][3], int clo, int chi)
{
    float p0, p1, p2, mB, q0, q1, q2;
    unpk(ru, p0, p1, p2, mB, q0, q1, q2);
    float dxb = XY ? (fi0 - (fi0 + (float)(r - SPANc)) * (1.0f / 6.0f)) : 0.0f;
#pragma unroll
    for (int c = 0; c < Gc; ++c) {
        if (c < clo || c > chi) continue;
        tap<XY>(p0, p1, p2, mB, q0, q1, q2, c0s[c], c1s[c], c2s[c], mA[c],
                xy_on, dy2, dxb + (float)c, eg[c][0], eg[c][1], eg[c][2]);
    }
}

// 3-phase window loop over staged LDS records (R0-proven shape).
template<bool XY>
__device__ __forceinline__ void window_loop(
    const uint4* sU4, int lbase,
    const float* c0s, const float* c1s, const float* c2s, const float* mA,
    bool xy_on, float dy2, float fi0, float eg[Gc][3])
{
#pragma unroll
    for (int r = 0; r < 3; ++r) {               // prologue (triangular): c <= r
        row_taps<XY>(sU4[lbase + r * TJ], r, c0s, c1s, c2s, mA,
                     xy_on, dy2, fi0, eg, 0, r);
    }
#pragma unroll 2
    for (int r = 3; r <= 22; ++r) {             // full rows: all 4 centers
        row_taps<XY>(sU4[lbase + r * TJ], r, c0s, c1s, c2s, mA,
                     xy_on, dy2, fi0, eg, 0, 3);
    }
#pragma unroll
    for (int r = 23; r <= 25; ++r) {            // epilogue (triangular): c >= r-22
        row_taps<XY>(sU4[lbase + r * TJ], r, c0s, c1s, c2s, mA,
                     xy_on, dy2, fi0, eg, r - 22, 3);
    }
}

// SELF-CONTAINED window kernel: prep is folded into the staging loop (each
// block softmax/packs its own 54x32 record tile from raw inputs — ~30x
// redundant across dj, ~+250 VALU/thread vs ~910 baseline) and the cvec
// center terms are recomputed in the epilogue. CE is owned by dj==11 blocks
// (each center pixel counted exactly once). Reduction: plain-store
// partial[bflat] — no atomics, no fences, no zero-init. Grid: (5,10,23).
__global__ __launch_bounds__(256, 5) void gcrf_kernel(
    const float* __restrict__ logit, const int* __restrict__ target,
    const float* __restrict__ image, const float* __restrict__ srcmap,
    const float* __restrict__ dstmap, float* __restrict__ partial)
{
    __shared__ uint4 sU4[NREC];

    int tx = threadIdx.x;                 // 0..31 (j)
    int ty = threadIdx.y;                 // 0..7  (i-group)
    int tid = ty * TJ + tx;
    int jx = blockIdx.x;
    int j  = jx * TJ + tx;
    int by = blockIdx.y;
    int b  = by / 5;
    int it = by - b * 5;
    int i0g = it * TI + ty * Gc;          // first center row of this thread
    int dj = blockIdx.z;                  // 0..22

    // ---- staging with on-the-fly prep ----
    int i_top  = it * TI - SPANc;         // global row of staged rr=0
    int j_left = jx * TJ + dj - SPANc;    // global col of staged cc=0
    for (int n = tid; n < NREC; n += 256) {
        int rr = n >> 5, cc = n & 31;
        int ii = i_top + rr, jj = j_left + cc;
        uint4 rec = make_uint4(0u, 0u, 0u, 0u);
        if ((unsigned)ii < (unsigned)Hn && (unsigned)jj < (unsigned)Wn) {
            int r = ii * Wn + jj;
            int p = b * HWn + r;
            const float* lg = logit + (size_t)b * Cn * HWn + r;
            float l0 = lg[0], l1 = lg[HWn], l2 = lg[2 * HWn];
            float m = fmaxf(l0, fmaxf(l1, l2));
            float e0 = __expf(l0 - m), e1 = __expf(l1 - m), e2 = __expf(l2 - m);
            float s = e0 + e1 + e2;
            float inv = 1.0f / s;
            float y0 = e0 * inv, y1 = e1 * inv, y2 = e2 * inv;
            const float* im = image + (size_t)b * 3 * HWn + r;
            float p0 = im[0], p1 = im[HWn], p2 = im[2 * HWn];
            float sv = srcmap[p];
            float Bv = (p0 * p0 + p1 * p1 + p2 * p2) * (100.0f * CA);
            rec = make_uint4(bf16pk(p0, p1), bf16pk(p2, -Bv),
                             bf16pk(sv * y0, sv * y1), bf16pk(sv * y2, 0.0f));
        }
        sU4[n] = rec;
    }
    __syncthreads();

    bool isxy = (jx == 0 && it == 0);     // block-uniform
    bool ceb  = (dj == SPANc);            // block-uniform CE owner

    int lbase = ty * Gc * TJ + tx;        // LDS index of (local row ty*Gc, col tx)
    float c0s[Gc], c1s[Gc], c2s[Gc], mA[Gc], kAe[Gc];
#pragma unroll
    for (int c = 0; c < Gc; ++c) {
        uint4 cu = sU4[lbase + (c + SPANc) * TJ];
        float cc0 = __uint_as_float(cu.x & 0xffff0000u);
        float cc1 = __uint_as_float(cu.x << 16);
        float cc2 = __uint_as_float(cu.y & 0xffff0000u);
        c0s[c] = cc0 * CX; c1s[c] = cc1 * CX; c2s[c] = cc2 * CX;
        mA[c] = -CA * fmaf(cc0, cc0, fmaf(cc1, cc1, cc2 * cc2));
        kAe[c] = isxy ? 1.0f : __builtin_amdgcn_exp2f(mA[c]);
    }

    // k_xy < 2.3e-29 unless both i<16 and j<16 (source-bug form: d = c - p/6)
    bool xy_on = (j < 16) && (i0g < 16);
    float dy = (float)j - (float)(j + dj - SPANc) * (1.0f / 6.0f);
    float dy2 = dy * dy;
    float fi0 = (float)i0g;

    float eg[Gc][3];
#pragma unroll
    for (int c = 0; c < Gc; ++c) { eg[c][0] = 0.f; eg[c][1] = 0.f; eg[c][2] = 0.f; }

    if (isxy) {   // only blocks where xy_on can hold
        window_loop<true>(sU4, lbase, c0s, c1s, c2s, mA, xy_on, dy2, fi0, eg);
    } else {
        window_loop<false>(sU4, lbase, c0s, c1s, c2s, mA, false, dy2, fi0, eg);
    }

    // ---- epilogue: recompute center softmax -> cvec terms (+ CE if owner) ----
    float contrib = 0.0f;
#pragma unroll
    for (int c = 0; c < Gc; ++c) {
        int r = (i0g + c) * Wn + j;
        int p = b * HWn + r;
        const float* lg = logit + (size_t)b * Cn * HWn + r;
        float l0 = lg[0], l1 = lg[HWn], l2 = lg[2 * HWn];
        float m = fmaxf(l0, fmaxf(l1, l2));
        float e0 = __expf(l0 - m), e1 = __expf(l1 - m), e2 = __expf(l2 - m);
        float s = e0 + e1 + e2;
        float inv = 1.0f / s;
        float y0 = e0 * inv, y1 = e1 * inv, y2 = e2 * inv;
        float dv = dstmap[p];
        float md = LAMc * (1.0f - dv) * INVN;
        float t0 = md * (1.0f - y0), t1 = md * (1.0f - y1), t2 = md * (1.0f - y2);
        float d = eg[c][0] * t0 + eg[c][1] * t1 + eg[c][2] * t2;
        contrib = fmaf(kAe[c], d, contrib);
        if (ceb) {
            float lse = m + __logf(s);
            int t = target[p];
            float lt = (t == 0) ? l0 : ((t == 1) ? l1 : l2);
            contrib += (lse - lt) * dv * INVN;
        }
    }

    float v = wave_reduce64(contrib);
    __shared__ float wsum[4];
    if ((tid & 63) == 0) wsum[tid >> 6] = v;
    __syncthreads();
    if (tid == 0) {
        int bflat = (blockIdx.z * gridDim.y + blockIdx.y) * gridDim.x + blockIdx.x;
        partial[bflat] = wsum[0] + wsum[1] + wsum[2] + wsum[3];
    }
}

// 1-block finalize: sum the 1150 block partials, plain-store out[0].
// Kernel boundary provides visibility of gcrf's plain stores.
__global__ __launch_bounds__(256) void finalize_kernel(
    const float* __restrict__ partial, float* __restrict__ out)
{
    int tid = threadIdx.x;
    float s = 0.0f;
    for (int k = tid; k < NBLK; k += 256) s += partial[k];
    float v = wave_reduce64(s);
    __shared__ float wsum[4];
    if ((tid & 63) == 0) wsum[tid >> 6] = v;
    __syncthreads();
    if (tid == 0) out[0] = wsum[0] + wsum[1] + wsum[2] + wsum[3];
}

extern "C" void kernel_launch(void* const* d_in, const int* in_sizes, int n_in,
                              void* d_out, int out_size, void* d_ws, size_t ws_size,
                              hipStream_t stream)
{
    const float* logit  = (const float*)d_in[0];
    const int*   target = (const int*)d_in[1];
    const float* image  = (const float*)d_in[2];
    const float* srcmap = (const float*)d_in[3];
    const float* dstmap = (const float*)d_in[4];
    float* out = (float*)d_out;

    float* partial = (float*)((char*)d_ws + 4096);   // 1150 block partials

    dim3 grid(Wn / TJ, (Hn / TI) * Bn, Kc);
    dim3 blk(TJ, 8);
    gcrf_kernel<<<grid, blk, 0, stream>>>(logit, target, image, srcmap, dstmap,
                                          partial);
    finalize_kernel<<<1, 256, 0, stream>>>(partial, out);
}

// Round 8
// 79.520 us; speedup vs baseline: 1.1338x; 1.0173x over previous
//
#include <hip/hip_runtime.h>

#define Bn 2
#define Cn 3
#define Hn 160
#define Wn 160
#define SPANc 11
#define Kc 23
#define HWn (Hn * Wn)
#define PW 182                 // padded dim: 160 + 2*11
#define PP (PW * PW)
#define LAMc 0.15f
#define INVN (1.0f / (float)(Bn * HWn))
#define TJ 32                  // j-tile width (= lanes 0..31)
#define Gc 4                   // centers per thread (vertical)
#define TI 32                  // i-tile height = 8 ty-groups * Gc
#define NROW (TI + Kc - 1)     // 54 staged rows
#define NREC (NROW * TJ)       // 1728 records in LDS (16 B each = 27.6 KB)
#define CEXP (-0.72134752f)    // -0.5 * log2(e)
#define CX   (14.42695041f)    // 20 * 0.72134752  (cross-term scale)
#define CA   (0.72134752f)
#define NPREP ((Bn * PP + 255) / 256)   // 259 prep blocks
#define NCELL 64               // spread accumulator cells (256 B apart)
#define CELLSTRIDE 64          // floats between cells

typedef float v2f __attribute__((ext_vector_type(2)));

__device__ __forceinline__ float wave_reduce64(float v) {
#pragma unroll
    for (int off = 32; off > 0; off >>= 1) v += __shfl_down(v, off, 64);
    return v;
}

// pack two floats as bf16 (rne) into one uint: a in high 16, b in low 16
__device__ __forceinline__ unsigned int bf16pk(float a, float b) {
    unsigned int ua = __float_as_uint(a), ub = __float_as_uint(b);
    ua += 0x7fffu + ((ua >> 16) & 1u);
    ub += 0x7fffu + ((ub >> 16) & 1u);
    return (ua & 0xffff0000u) | (ub >> 16);
}

// Fused: zero halo + softmax/pack interior + CE block-partials (pre-scaled) +
// zero the 64 spread cells. Record uint4: [pk(p0,p1), pk(p2,mB), pk(q0,q1), pk(q2,0)]
__global__ __launch_bounds__(256) void prep_kernel(
    const float* __restrict__ logit, const int* __restrict__ target,
    const float* __restrict__ image, const float* __restrict__ srcmap,
    const float* __restrict__ dstmap, uint4* __restrict__ gU4,
    float4* __restrict__ cvec, float* __restrict__ pc, float* __restrict__ cells)
{
    int idx = blockIdx.x * 256 + threadIdx.x;
    float ce = 0.0f;
    if (idx < NCELL) cells[idx * CELLSTRIDE] = 0.0f;   // gcrf runs after (stream order)
    if (idx < Bn * PP) {
        int b   = idx / PP;
        int rem = idx - b * PP;
        int ip  = rem / PW;
        int jp  = rem - ip * PW;
        int i = ip - SPANc, j = jp - SPANc;
        if ((unsigned)i < (unsigned)Hn && (unsigned)j < (unsigned)Wn) {
            int r = i * Wn + j;
            int p = b * HWn + r;
            const float* lg = logit + (size_t)b * Cn * HWn + r;
            float l0 = lg[0], l1 = lg[HWn], l2 = lg[2 * HWn];
            float m = fmaxf(l0, fmaxf(l1, l2));
            float e0 = __expf(l0 - m), e1 = __expf(l1 - m), e2 = __expf(l2 - m);
            float s = e0 + e1 + e2;
            float inv = 1.0f / s;
            float y0 = e0 * inv, y1 = e1 * inv, y2 = e2 * inv;
            float lse = m + __logf(s);

            const float* im = image + (size_t)b * 3 * HWn + r;
            float p0 = im[0], p1 = im[HWn], p2 = im[2 * HWn];
            float sv = srcmap[p];
            float dv = dstmap[p];

            float B = (p0 * p0 + p1 * p1 + p2 * p2) * (100.0f * CA);
            gU4[idx] = make_uint4(bf16pk(p0, p1), bf16pk(p2, -B),
                                  bf16pk(sv * y0, sv * y1), bf16pk(sv * y2, 0.0f));

            float md = LAMc * (1.0f - dv) * INVN;
            cvec[p] = make_float4(md * (1.0f - y0), md * (1.0f - y1),
                                  md * (1.0f - y2), 0.0f);

            int t = target[p];
            float lt = (t == 0) ? l0 : ((t == 1) ? l1 : l2);
            ce = (lse - lt) * dv * INVN;
        } else {
            gU4[idx] = make_uint4(0u, 0u, 0u, 0u);
        }
    }

    float v = wave_reduce64(ce);
    __shared__ float wsum[4];
    int tid = threadIdx.x;
    if ((tid & 63) == 0) wsum[tid >> 6] = v;
    __syncthreads();
    if (tid == 0) pc[blockIdx.x] = wsum[0] + wsum[1] + wsum[2] + wsum[3];
}

// ---- scalar edge-row path (rows 0..2 and 23..25; also the full XY scalar form) ----
template<bool XY>
__device__ __forceinline__ void tap(float p0, float p1, float p2, float mB,
                                    float q0, float q1, float q2,
                                    float c0s, float c1s, float c2s, float mA,
                                    bool xy_on, float dy2, float dxv,
                                    float& e0, float& e1, float& e2)
{
    float e = fmaf(c0s, p0, fmaf(c1s, p1, fmaf(c2s, p2, mB)));
    float k;
    if constexpr (XY) {
        k = __builtin_amdgcn_exp2f(e + mA);
        if (xy_on) k += __builtin_amdgcn_exp2f(fmaf(dxv, dxv, dy2) * CEXP);
    } else {
        k = __builtin_amdgcn_exp2f(e);   // kA factored into epilogue
    }
    e0 = fmaf(k, q0, e0);
    e1 = fmaf(k, q1, e1);
    e2 = fmaf(k, q2, e2);
}

template<bool XY>
__device__ __forceinline__ void row_taps(uint4 ru, int r,
    const float* c0s, const float* c1s, const float* c2s, const float* mA,
    bool xy_on, float dy2, float fi0, float eg[Gc][3], int clo, int chi)
{
    float p0 = __uint_as_float(ru.x & 0xffff0000u);
    float p1 = __uint_as_float(ru.x << 16);
    float p2 = __uint_as_float(ru.y & 0xffff0000u);
    float mB = __uint_as_float(ru.y << 16);
    float q0 = __uint_as_float(ru.z & 0xffff0000u);
    float q1 = __uint_as_float(ru.z << 16);
    float q2 = __uint_as_float(ru.w & 0xffff0000u);
    float dxb = XY ? (fi0 - (fi0 + (float)(r - SPANc)) * (1.0f / 6.0f)) : 0.0f;
#pragma unroll
    for (int c = 0; c < Gc; ++c) {
        if (c < clo || c > chi) continue;
        tap<XY>(p0, p1, p2, mB, q0, q1, q2, c0s[c], c1s[c], c2s[c], mA[c],
                xy_on, dy2, dxb + (float)c, eg[c][0], eg[c][1], eg[c][2]);
    }
}

// ---- packed main-row path (rows 3..22, all 4 centers) ----
// v_pk_fma_f32: D = S0*S1 + S2, per 32-bit lane; op_sel_hi[i]=0 broadcasts the
// low dword of source i to the high lane. Dots: centers packed (0,1)/(2,3),
// p/mB broadcast. Acc: accumulators packed by center-pair per channel, q
// broadcast. 19 VALU + 4 trans per row vs 31 + 4 scalar.
template<bool XY>
__device__ __forceinline__ void row_main(uint4 ru, int r,
    const float* mA,
    v2f C0_01, v2f C0_23, v2f C1_01, v2f C1_23, v2f C2_01, v2f C2_23,
    bool xy_on, float dy2, float fi0,
    v2f& A0, v2f& A1, v2f& A2, v2f& B0, v2f& B1, v2f& B2)
{
    v2f p0p, p1p, p2p, mBp, q0p, q1p, q2p;
    p0p[0] = __uint_as_float(ru.x & 0xffff0000u);
    p1p[0] = __uint_as_float(ru.x << 16);
    p2p[0] = __uint_as_float(ru.y & 0xffff0000u);
    mBp[0] = __uint_as_float(ru.y << 16);
    q0p[0] = __uint_as_float(ru.z & 0xffff0000u);
    q1p[0] = __uint_as_float(ru.z << 16);
    q2p[0] = __uint_as_float(ru.w & 0xffff0000u);

    v2f e01, e23;
    asm("v_pk_fma_f32 %0, %1, %2, %3 op_sel_hi:[1,0,0]"
        : "=v"(e01) : "v"(C2_01), "v"(p2p), "v"(mBp));
    asm("v_pk_fma_f32 %0, %1, %2, %0 op_sel_hi:[1,0,1]"
        : "+v"(e01) : "v"(C1_01), "v"(p1p));
    asm("v_pk_fma_f32 %0, %1, %2, %0 op_sel_hi:[1,0,1]"
        : "+v"(e01) : "v"(C0_01), "v"(p0p));
    asm("v_pk_fma_f32 %0, %1, %2, %3 op_sel_hi:[1,0,0]"
        : "=v"(e23) : "v"(C2_23), "v"(p2p), "v"(mBp));
    asm("v_pk_fma_f32 %0, %1, %2, %0 op_sel_hi:[1,0,1]"
        : "+v"(e23) : "v"(C1_23), "v"(p1p));
    asm("v_pk_fma_f32 %0, %1, %2, %0 op_sel_hi:[1,0,1]"
        : "+v"(e23) : "v"(C0_23), "v"(p0p));

    if constexpr (XY) {
        // 50/1150 blocks: scalar finish with mA + conditional xy term
        float q0 = q0p[0], q1 = q1p[0], q2 = q2p[0];
        float dxb = fi0 - (fi0 + (float)(r - SPANc)) * (1.0f / 6.0f);
        float e0v = e01[0], e1v = e01[1], e2v = e23[0], e3v = e23[1];
        float k0 = __builtin_amdgcn_exp2f(e0v + mA[0]);
        float k1 = __builtin_amdgcn_exp2f(e1v + mA[1]);
        float k2 = __builtin_amdgcn_exp2f(e2v + mA[2]);
        float k3 = __builtin_amdgcn_exp2f(e3v + mA[3]);
        if (xy_on) {
            float d0 = dxb + 0.f, d1 = dxb + 1.f, d2 = dxb + 2.f, d3 = dxb + 3.f;
            k0 += __builtin_amdgcn_exp2f(fmaf(d0, d0, dy2) * CEXP);
            k1 += __builtin_amdgcn_exp2f(fmaf(d1, d1, dy2) * CEXP);
            k2 += __builtin_amdgcn_exp2f(fmaf(d2, d2, dy2) * CEXP);
            k3 += __builtin_amdgcn_exp2f(fmaf(d3, d3, dy2) * CEXP);
        }
        A0[0] = fmaf(k0, q0, A0[0]); A1[0] = fmaf(k0, q1, A1[0]); A2[0] = fmaf(k0, q2, A2[0]);
        A0[1] = fmaf(k1, q0, A0[1]); A1[1] = fmaf(k1, q1, A1[1]); A2[1] = fmaf(k1, q2, A2[1]);
        B0[0] = fmaf(k2, q0, B0[0]); B1[0] = fmaf(k2, q1, B1[0]); B2[0] = fmaf(k2, q2, B2[0]);
        B0[1] = fmaf(k3, q0, B0[1]); B1[1] = fmaf(k3, q1, B1[1]); B2[1] = fmaf(k3, q2, B2[1]);
    } else {
        v2f k01, k23;
        k01[0] = __builtin_amdgcn_exp2f(e01[0]);
        k01[1] = __builtin_amdgcn_exp2f(e01[1]);
        k23[0] = __builtin_amdgcn_exp2f(e23[0]);
        k23[1] = __builtin_amdgcn_exp2f(e23[1]);
        asm("v_pk_fma_f32 %0, %1, %2, %0 op_sel_hi:[1,0,1]"
            : "+v"(A0) : "v"(k01), "v"(q0p));
        asm("v_pk_fma_f32 %0, %1, %2, %0 op_sel_hi:[1,0,1]"
            : "+v"(A1) : "v"(k01), "v"(q1p));
        asm("v_pk_fma_f32 %0, %1, %2, %0 op_sel_hi:[1,0,1]"
            : "+v"(A2) : "v"(k01), "v"(q2p));
        asm("v_pk_fma_f32 %0, %1, %2, %0 op_sel_hi:[1,0,1]"
            : "+v"(B0) : "v"(k23), "v"(q0p));
        asm("v_pk_fma_f32 %0, %1, %2, %0 op_sel_hi:[1,0,1]"
            : "+v"(B1) : "v"(k23), "v"(q1p));
        asm("v_pk_fma_f32 %0, %1, %2, %0 op_sel_hi:[1,0,1]"
            : "+v"(B2) : "v"(k23), "v"(q2p));
    }
}

// Window kernel. Grid/LDS/staging/reduction identical to the measured-best R4.
__global__ __launch_bounds__(256, 5) void gcrf_kernel(
    const uint4* __restrict__ gU4, const float4* __restrict__ cvec,
    float* __restrict__ cells)
{
    __shared__ uint4 sU4[NREC];

    int tx = threadIdx.x;                 // 0..31 (j)
    int ty = threadIdx.y;                 // 0..7  (i-group)
    int tid = ty * TJ + tx;
    int jx = blockIdx.x;
    int j  = jx * TJ + tx;
    int by = blockIdx.y;
    int b  = by / 5;
    int it = by - b * 5;
    int i0g = it * TI + ty * Gc;          // first center row of this thread
    int dj = blockIdx.z;                  // 0..22

    size_t g0 = (size_t)b * PP + (size_t)(it * TI) * PW + (jx * TJ + dj);
    for (int n = tid; n < NREC; n += 256) {
        int rr = n >> 5, cc = n & 31;
        sU4[n] = gU4[g0 + (size_t)rr * PW + cc];
    }
    __syncthreads();

    bool isxy = (jx == 0 && it == 0);     // block-uniform

    int lbase = ty * Gc * TJ + tx;        // LDS index of (local row ty*Gc, col tx)
    float c0s[Gc], c1s[Gc], c2s[Gc], mA[Gc], kAe[Gc];
#pragma unroll
    for (int c = 0; c < Gc; ++c) {
        uint4 cu = sU4[lbase + (c + SPANc) * TJ];
        float cc0 = __uint_as_float(cu.x & 0xffff0000u);
        float cc1 = __uint_as_float(cu.x << 16);
        float cc2 = __uint_as_float(cu.y & 0xffff0000u);
        c0s[c] = cc0 * CX; c1s[c] = cc1 * CX; c2s[c] = cc2 * CX;
        mA[c] = -CA * fmaf(cc0, cc0, fmaf(cc1, cc1, cc2 * cc2));
        kAe[c] = isxy ? 1.0f : __builtin_amdgcn_exp2f(mA[c]);
    }
    v2f C0_01, C0_23, C1_01, C1_23, C2_01, C2_23;
    C0_01[0] = c0s[0]; C0_01[1] = c0s[1]; C0_23[0] = c0s[2]; C0_23[1] = c0s[3];
    C1_01[0] = c1s[0]; C1_01[1] = c1s[1]; C1_23[0] = c1s[2]; C1_23[1] = c1s[3];
    C2_01[0] = c2s[0]; C2_01[1] = c2s[1]; C2_23[0] = c2s[2]; C2_23[1] = c2s[3];

    // k_xy < 2.3e-29 unless both i<16 and j<16 (source-bug form: d = c - p/6)
    bool xy_on = (j < 16) && (i0g < 16);
    float dy = (float)j - (float)(j + dj - SPANc) * (1.0f / 6.0f);
    float dy2 = dy * dy;
    float fi0 = (float)i0g;

    // edge-row scalar accumulators
    float sA[Gc][3];
#pragma unroll
    for (int c = 0; c < Gc; ++c) { sA[c][0] = 0.f; sA[c][1] = 0.f; sA[c][2] = 0.f; }

    // prologue rows 0..2 (triangular, scalar)
    if (isxy) {
#pragma unroll
        for (int r = 0; r < 3; ++r)
            row_taps<true>(sU4[lbase + r * TJ], r, c0s, c1s, c2s, mA,
                           xy_on, dy2, fi0, sA, 0, r);
    } else {
#pragma unroll
        for (int r = 0; r < 3; ++r)
            row_taps<false>(sU4[lbase + r * TJ], r, c0s, c1s, c2s, mA,
                            false, dy2, fi0, sA, 0, r);
    }

    // fold prologue into packed accumulators; re-zero sA for epilogue rows
    v2f A0, A1, A2, B0, B1, B2;
    A0[0] = sA[0][0]; A0[1] = sA[1][0]; B0[0] = sA[2][0]; B0[1] = sA[3][0];
    A1[0] = sA[0][1]; A1[1] = sA[1][1]; B1[0] = sA[2][1]; B1[1] = sA[3][1];
    A2[0] = sA[0][2]; A2[1] = sA[1][2]; B2[0] = sA[2][2]; B2[1] = sA[3][2];
#pragma unroll
    for (int c = 0; c < Gc; ++c) { sA[c][0] = 0.f; sA[c][1] = 0.f; sA[c][2] = 0.f; }

    // main rows 3..22 (packed)
    if (isxy) {
#pragma unroll 2
        for (int r = 3; r <= 22; ++r)
            row_main<true>(sU4[lbase + r * TJ], r, mA,
                           C0_01, C0_23, C1_01, C1_23, C2_01, C2_23,
                           xy_on, dy2, fi0, A0, A1, A2, B0, B1, B2);
    } else {
#pragma unroll 2
        for (int r = 3; r <= 22; ++r)
            row_main<false>(sU4[lbase + r * TJ], r, mA,
                            C0_01, C0_23, C1_01, C1_23, C2_01, C2_23,
                            false, dy2, fi0, A0, A1, A2, B0, B1, B2);
    }

    // epilogue rows 23..25 (triangular, scalar)
    if (isxy) {
#pragma unroll
        for (int r = 23; r <= 25; ++r)
            row_taps<true>(sU4[lbase + r * TJ], r, c0s, c1s, c2s, mA,
                           xy_on, dy2, fi0, sA, r - 22, 3);
    } else {
#pragma unroll
        for (int r = 23; r <= 25; ++r)
            row_taps<false>(sU4[lbase + r * TJ], r, c0s, c1s, c2s, mA,
                            false, dy2, fi0, sA, r - 22, 3);
    }

    // epilogue: cvec holds lam*(1-dst)*(1-y_c)/(B*HW); kAe folds back exp2(mA)
    const float4* cv = cvec + ((size_t)b * HWn + (size_t)i0g * Wn + j);
    float contrib = 0.0f;
    {
        float4 t = cv[0];
        float d = (A0[0] + sA[0][0]) * t.x + (A1[0] + sA[0][1]) * t.y
                + (A2[0] + sA[0][2]) * t.z;
        contrib = fmaf(kAe[0], d, contrib);
    }
    {
        float4 t = cv[Wn];
        float d = (A0[1] + sA[1][0]) * t.x + (A1[1] + sA[1][1]) * t.y
                + (A2[1] + sA[1][2]) * t.z;
        contrib = fmaf(kAe[1], d, contrib);
    }
    {
        float4 t = cv[2 * Wn];
        float d = (B0[0] + sA[2][0]) * t.x + (B1[0] + sA[2][1]) * t.y
                + (B2[0] + sA[2][2]) * t.z;
        contrib = fmaf(kAe[2], d, contrib);
    }
    {
        float4 t = cv[3 * Wn];
        float d = (B0[1] + sA[3][0]) * t.x + (B1[1] + sA[3][1]) * t.y
                + (B2[1] + sA[3][2]) * t.z;
        contrib = fmaf(kAe[3], d, contrib);
    }

    float v = wave_reduce64(contrib);
    __shared__ float wsum[4];
    if ((tid & 63) == 0) wsum[tid >> 6] = v;
    __syncthreads();
    if (tid == 0) {
        int bflat = (blockIdx.z * gridDim.y + blockIdx.y) * gridDim.x + blockIdx.x;
        atomicAdd(cells + (size_t)(bflat & (NCELL - 1)) * CELLSTRIDE,
                  wsum[0] + wsum[1] + wsum[2] + wsum[3]);
    }
}

// Single-wave finalize: sum 64 spread cells + 259 CE partials, plain-store out.
__global__ __launch_bounds__(64) void finalize_kernel(
    const float* __restrict__ cells, const float* __restrict__ pc,
    float* __restrict__ out)
{
    int t = threadIdx.x;
    float s = cells[(size_t)t * CELLSTRIDE];
    for (int k = t; k < NPREP; k += 64) s += pc[k];
    float v = wave_reduce64(s);
    if (t == 0) out[0] = v;
}

extern "C" void kernel_launch(void* const* d_in, const int* in_sizes, int n_in,
                              void* d_out, int out_size, void* d_ws, size_t ws_size,
                              hipStream_t stream)
{
    const float* logit  = (const float*)d_in[0];
    const int*   target = (const int*)d_in[1];
    const float* image  = (const float*)d_in[2];
    const float* srcmap = (const float*)d_in[3];
    const float* dstmap = (const float*)d_in[4];
    float* out = (float*)d_out;

    const size_t NRECG = (size_t)Bn * PP;   // 66,248 padded records
    float*  pc    = (float*)((char*)d_ws + 256);                 // 259 CE partials
    float*  cells = (float*)((char*)d_ws + 4096);                // 64 cells, 256 B apart
    uint4*  gU4   = (uint4*)((char*)d_ws + 4096 + 16384);
    float4* cvec  = (float4*)((char*)d_ws + 4096 + 16384 + NRECG * 16);

    prep_kernel<<<NPREP, 256, 0, stream>>>(logit, target, image, srcmap, dstmap,
                                           gU4, cvec, pc, cells);
    dim3 grid(Wn / TJ, (Hn / TI) * Bn, Kc);
    dim3 blk(TJ, 8);
    gcrf_kernel<<<grid, blk, 0, stream>>>(gU4, cvec, cells);
    finalize_kernel<<<1, 64, 0, stream>>>(cells, pc, out);
}

// Round 12
// 79.419 us; speedup vs baseline: 1.1352x; 1.0013x over previous
//
#include <hip/hip_runtime.h>

#define Bn 2
#define Cn 3
#define Hn 160
#define Wn 160
#define SPANc 11
#define Kc 23
#define HWn (Hn * Wn)
#define PW 182                 // padded dim: 160 + 2*11
#define PP (PW * PW)
#define LAMc 0.15f
#define INVN (1.0f / (float)(Bn * HWn))
#define TJ 32                  // j-tile width (= lanes 0..31)
#define Gc 4                   // centers per thread (vertical)
#define TI 32                  // i-tile height = 8 ty-groups * Gc
#define CEXP (-0.72134752f)    // -0.5 * log2(e)
#define CX   (14.42695041f)    // 20 * 0.72134752  (cross-term scale)
#define CA   (0.72134752f)
#define NPREP ((Bn * PP + 255) / 256)   // 259 prep blocks
#define NCELL 64               // spread accumulator cells (256 B apart)
#define CELLSTRIDE 64          // floats between cells

__device__ __forceinline__ float wave_reduce64(float v) {
#pragma unroll
    for (int off = 32; off > 0; off >>= 1) v += __shfl_down(v, off, 64);
    return v;
}

// pack two floats as bf16 (rne) into one uint: a in high 16, b in low 16
__device__ __forceinline__ unsigned int bf16pk(float a, float b) {
    unsigned int ua = __float_as_uint(a), ub = __float_as_uint(b);
    ua += 0x7fffu + ((ua >> 16) & 1u);
    ub += 0x7fffu + ((ub >> 16) & 1u);
    return (ua & 0xffff0000u) | (ub >> 16);
}

// Fused: zero halo + softmax/pack interior + CE block-partials (pre-scaled) +
// zero the 64 spread cells. Record uint4: [pk(p0,p1), pk(p2,mB), pk(q0,q1), pk(q2,0)]
__global__ __launch_bounds__(256) void prep_kernel(
    const float* __restrict__ logit, const int* __restrict__ target,
    const float* __restrict__ image, const float* __restrict__ srcmap,
    const float* __restrict__ dstmap, uint4* __restrict__ gU4,
    float4* __restrict__ cvec, float* __restrict__ pc, float* __restrict__ cells)
{
    int idx = blockIdx.x * 256 + threadIdx.x;
    float ce = 0.0f;
    if (idx < NCELL) cells[idx * CELLSTRIDE] = 0.0f;   // gcrf runs after (stream order)
    if (idx < Bn * PP) {
        int b   = idx / PP;
        int rem = idx - b * PP;
        int ip  = rem / PW;
        int jp  = rem - ip * PW;
        int i = ip - SPANc, j = jp - SPANc;
        if ((unsigned)i < (unsigned)Hn && (unsigned)j < (unsigned)Wn) {
            int r = i * Wn + j;
            int p = b * HWn + r;
            const float* lg = logit + (size_t)b * Cn * HWn + r;
            float l0 = lg[0], l1 = lg[HWn], l2 = lg[2 * HWn];
            float m = fmaxf(l0, fmaxf(l1, l2));
            float e0 = __expf(l0 - m), e1 = __expf(l1 - m), e2 = __expf(l2 - m);
            float s = e0 + e1 + e2;
            float inv = 1.0f / s;
            float y0 = e0 * inv, y1 = e1 * inv, y2 = e2 * inv;
            float lse = m + __logf(s);

            const float* im = image + (size_t)b * 3 * HWn + r;
            float p0 = im[0], p1 = im[HWn], p2 = im[2 * HWn];
            float sv = srcmap[p];
            float dv = dstmap[p];

            float B = (p0 * p0 + p1 * p1 + p2 * p2) * (100.0f * CA);
            gU4[idx] = make_uint4(bf16pk(p0, p1), bf16pk(p2, -B),
                                  bf16pk(sv * y0, sv * y1), bf16pk(sv * y2, 0.0f));

            float md = LAMc * (1.0f - dv) * INVN;
            cvec[p] = make_float4(md * (1.0f - y0), md * (1.0f - y1),
                                  md * (1.0f - y2), 0.0f);

            int t = target[p];
            float lt = (t == 0) ? l0 : ((t == 1) ? l1 : l2);
            ce = (lse - lt) * dv * INVN;
        } else {
            gU4[idx] = make_uint4(0u, 0u, 0u, 0u);
        }
    }

    float v = wave_reduce64(ce);
    __shared__ float wsum[4];
    int tid = threadIdx.x;
    if ((tid & 63) == 0) wsum[tid >> 6] = v;
    __syncthreads();
    if (tid == 0) pc[blockIdx.x] = wsum[0] + wsum[1] + wsum[2] + wsum[3];
}

// One tap (proven scalar form). Non-XY: kA-factored — k = exp2(c.p + mB);
// per-center exp2(mA) applied once in the epilogue. XY: exact form + xy term.
template<bool XY>
__device__ __forceinline__ void tap(float p0, float p1, float p2, float mB,
                                    float q0, float q1, float q2,
                                    float c0s, float c1s, float c2s, float mA,
                                    bool xy_on, float dy2, float dxv,
                                    float& e0, float& e1, float& e2)
{
    float e = fmaf(c0s, p0, fmaf(c1s, p1, fmaf(c2s, p2, mB)));
    float k;
    if constexpr (XY) {
        k = __builtin_amdgcn_exp2f(e + mA);
        if (xy_on) k += __builtin_amdgcn_exp2f(fmaf(dxv, dxv, dy2) * CEXP);
    } else {
        k = __builtin_amdgcn_exp2f(e);
    }
    e0 = fmaf(k, q0, e0);
    e1 = fmaf(k, q1, e1);
    e2 = fmaf(k, q2, e2);
}

template<bool XY>
__device__ __forceinline__ void row_taps(uint4 ru, int r,
    const float* c0s, const float* c1s, const float* c2s, const float* mA,
    bool xy_on, float dy2, float fi0, float eg[Gc][3], int clo, int chi)
{
    float p0 = __uint_as_float(ru.x & 0xffff0000u);
    float p1 = __uint_as_float(ru.x << 16);
    float p2 = __uint_as_float(ru.y & 0xffff0000u);
    float mB = __uint_as_float(ru.y << 16);
    float q0 = __uint_as_float(ru.z & 0xffff0000u);
    float q1 = __uint_as_float(ru.z << 16);
    float q2 = __uint_as_float(ru.w & 0xffff0000u);
    float dxb = XY ? (fi0 - (fi0 + (float)(r - SPANc)) * (1.0f / 6.0f)) : 0.0f;
#pragma unroll
    for (int c = 0; c < Gc; ++c) {
        if (c < clo || c > chi) continue;
        tap<XY>(p0, p1, p2, mB, q0, q1, q2, c0s[c], c1s[c], c2s[c], mA[c],
                xy_on, dy2, dxb + (float)c, eg[c][0], eg[c][1], eg[c][2]);
    }
}

// 3-phase window loop reading rows DIRECTLY from global (L2-resident gU4).
// gbase points at this thread's local row 0 (padded row i0g, padded col
// jx*TJ + dj + tx); rows stride PW. Lane-consecutive cols -> coalesced loads.
template<bool XY>
__device__ __forceinline__ void window_loop(
    const uint4* __restrict__ gbase,
    const float* c0s, const float* c1s, const float* c2s, const float* mA,
    bool xy_on, float dy2, float fi0, float eg[Gc][3])
{
#pragma unroll
    for (int r = 0; r < 3; ++r) {               // prologue (triangular): c <= r
        row_taps<XY>(gbase[(size_t)r * PW], r, c0s, c1s, c2s, mA,
                     xy_on, dy2, fi0, eg, 0, r);
    }
#pragma unroll 2
    for (int r = 3; r <= 22; ++r) {             // full rows: all 4 centers
        row_taps<XY>(gbase[(size_t)r * PW], r, c0s, c1s, c2s, mA,
                     xy_on, dy2, fi0, eg, 0, 3);
    }
#pragma unroll
    for (int r = 23; r <= 25; ++r) {            // epilogue (triangular): c >= r-22
        row_taps<XY>(gbase[(size_t)r * PW], r, c0s, c1s, c2s, mA,
                     xy_on, dy2, fi0, eg, r - 22, 3);
    }
}

// Window kernel, LDS-FREE. Grid: (5, 5*B, 23) = 1150 blocks. Block (32,8).
// gU4 (1.06 MB) is fully L2-resident; each thread reads its 26 window records
// + 4 center records directly from global — no staging, no __syncthreads,
// no LDS. Spread-cell reduction unchanged.
__global__ __launch_bounds__(256, 5) void gcrf_kernel(
    const uint4* __restrict__ gU4, const float4* __restrict__ cvec,
    float* __restrict__ cells)
{
    int tx = threadIdx.x;                 // 0..31 (j)
    int ty = threadIdx.y;                 // 0..7  (i-group)
    int tid = ty * TJ + tx;
    int jx = blockIdx.x;
    int j  = jx * TJ + tx;
    int by = blockIdx.y;
    int b  = by / 5;
    int it = by - b * 5;
    int i0g = it * TI + ty * Gc;          // first center row of this thread
    int dj = blockIdx.z;                  // 0..22

    // window base: padded row i0g (= interior i0g - SPANc), padded col j + dj - SPANc
    const uint4* gbase = gU4 + (size_t)b * PP + (size_t)i0g * PW
                             + (size_t)(jx * TJ + dj) + tx;
    // center base: padded row i0g + SPANc, padded col j + SPANc
    const uint4* gC = gU4 + (size_t)b * PP + (size_t)(i0g + SPANc) * PW
                          + (size_t)(j + SPANc);

    bool isxy = (jx == 0 && it == 0);     // block-uniform

    float c0s[Gc], c1s[Gc], c2s[Gc], mA[Gc], kAe[Gc];
#pragma unroll
    for (int c = 0; c < Gc; ++c) {
        uint4 cu = gC[(size_t)c * PW];
        float cc0 = __uint_as_float(cu.x & 0xffff0000u);
        float cc1 = __uint_as_float(cu.x << 16);
        float cc2 = __uint_as_float(cu.y & 0xffff0000u);
        c0s[c] = cc0 * CX; c1s[c] = cc1 * CX; c2s[c] = cc2 * CX;
        mA[c] = -CA * fmaf(cc0, cc0, fmaf(cc1, cc1, cc2 * cc2));
        kAe[c] = isxy ? 1.0f : __builtin_amdgcn_exp2f(mA[c]);
    }

    // k_xy < 2.3e-29 unless both i<16 and j<16 (source-bug form: d = c - p/6)
    bool xy_on = (j < 16) && (i0g < 16);
    float dy = (float)j - (float)(j + dj - SPANc) * (1.0f / 6.0f);
    float dy2 = dy * dy;
    float fi0 = (float)i0g;

    float eg[Gc][3];
#pragma unroll
    for (int c = 0; c < Gc; ++c) { eg[c][0] = 0.f; eg[c][1] = 0.f; eg[c][2] = 0.f; }

    if (isxy) {   // only blocks where xy_on can hold
        window_loop<true>(gbase, c0s, c1s, c2s, mA, xy_on, dy2, fi0, eg);
    } else {
        window_loop<false>(gbase, c0s, c1s, c2s, mA, false, dy2, fi0, eg);
    }

    // epilogue: cvec holds lam*(1-dst)*(1-y_c)/(B*HW); kAe folds back exp2(mA)
    const float4* cv = cvec + ((size_t)b * HWn + (size_t)i0g * Wn + j);
    float contrib = 0.0f;
#pragma unroll
    for (int c = 0; c < Gc; ++c) {
        float4 t = cv[(size_t)c * Wn];
        float d = eg[c][0] * t.x + eg[c][1] * t.y + eg[c][2] * t.z;
        contrib = fmaf(kAe[c], d, contrib);
    }

    float v = wave_reduce64(contrib);
    __shared__ float wsum[4];
    if ((tid & 63) == 0) wsum[tid >> 6] = v;
    __syncthreads();
    if (tid == 0) {
        int bflat = (blockIdx.z * gridDim.y + blockIdx.y) * gridDim.x + blockIdx.x;
        atomicAdd(cells + (size_t)(bflat & (NCELL - 1)) * CELLSTRIDE,
                  wsum[0] + wsum[1] + wsum[2] + wsum[3]);
    }
}

// Single-wave finalize: sum 64 spread cells + 259 CE partials, plain-store out.
__global__ __launch_bounds__(64) void finalize_kernel(
    const float* __restrict__ cells, const float* __restrict__ pc,
    float* __restrict__ out)
{
    int t = threadIdx.x;
    float s = cells[(size_t)t * CELLSTRIDE];
    for (int k = t; k < NPREP; k += 64) s += pc[k];
    float v = wave_reduce64(s);
    if (t == 0) out[0] = v;
}

extern "C" void kernel_launch(void* const* d_in, const int* in_sizes, int n_in,
                              void* d_out, int out_size, void* d_ws, size_t ws_size,
                              hipStream_t stream)
{
    const float* logit  = (const float*)d_in[0];
    const int*   target = (const int*)d_in[1];
    const float* image  = (const float*)d_in[2];
    const float* srcmap = (const float*)d_in[3];
    const float* dstmap = (const float*)d_in[4];
    float* out = (float*)d_out;

    const size_t NRECG = (size_t)Bn * PP;   // 66,248 padded records
    float*  pc    = (float*)((char*)d_ws + 256);                 // 259 CE partials
    float*  cells = (float*)((char*)d_ws + 4096);                // 64 cells, 256 B apart
    uint4*  gU4   = (uint4*)((char*)d_ws + 4096 + 16384);
    float4* cvec  = (float4*)((char*)d_ws + 4096 + 16384 + NRECG * 16);

    prep_kernel<<<NPREP, 256, 0, stream>>>(logit, target, image, srcmap, dstmap,
                                           gU4, cvec, pc, cells);
    dim3 grid(Wn / TJ, (Hn / TI) * Bn, Kc);
    dim3 blk(TJ, 8);
    gcrf_kernel<<<grid, blk, 0, stream>>>(gU4, cvec, cells);
    finalize_kernel<<<1, 64, 0, stream>>>(cells, pc, out);
}